// Round 2
// baseline (145.583 us; speedup 1.0000x reference)
//
#include <hip/hip_runtime.h>
#include <stdint.h>

typedef uint16_t u16;
typedef __attribute__((ext_vector_type(8))) short    bf16x8;  // 8 bf16 (4 VGPRs)
typedef __attribute__((ext_vector_type(8))) uint16_t u16x8;
typedef __attribute__((ext_vector_type(4))) float    f32x4;

#define B_    2
#define N_    100000
#define K_    26
#define CIN_  32
#define COUT_ 32

#define XT_ROWS  (N_ + 1)
#define XT_BYTES ((size_t)B_ * XT_ROWS * CIN_ * 2)   // 12,800,128 bytes

// ---- prep kernel geometry ----
#define TCHUNK      64
#define TBLK_PER_B  ((N_ + TCHUNK - 1) / TCHUNK)     // 1563
#define TBLKS       (B_ * TBLK_PER_B)                // 3126
#define WELEMS      (COUT_ * CIN_ * K_)              // 26624
#define WBLKS       13                               // 13 * 2048 = 26624
#define PREP_GRID   (TBLKS + 1 + WBLKS)

// ---- conv kernel geometry ----
#define NPB         256                              // nodes per block
#define CBLK_PER_B  ((N_ + NPB - 1) / NPB)           // 391
#define CONV_GRID   (B_ * CBLK_PER_B)                // 782
#define WPITCH      840                              // 832 + 8 pad (bf16 elems)

__device__ __forceinline__ u16 f2bf(float f) {
    union { float f; uint32_t u; } v; v.f = f;
    return (u16)((v.u + 0x7FFFu + ((v.u >> 16) & 1u)) >> 16);  // RNE
}

// Transpose inp [B][CIN][N] f32 -> xt [B][N+1][CIN] bf16 (64B rows),
// write fill row at n==N, convert W -> bf16.
__global__ __launch_bounds__(256) void prep_kernel(
    const float* __restrict__ inp, const float* __restrict__ W,
    const float* __restrict__ fill, u16* __restrict__ xt, u16* __restrict__ Wb)
{
    int tid = threadIdx.x;
    int blk = blockIdx.x;
    if (blk >= TBLKS) {
        int job = blk - TBLKS;
        if (job == 0) {
            if (tid < B_ * CIN_) {
                int b = tid >> 5, c = tid & 31;
                xt[((size_t)b * XT_ROWS + N_) * CIN_ + c] = f2bf(fill[c]);
            }
        } else {
            int base = (job - 1) * 2048 + tid * 8;   // exact: 13*2048 = 26624
            const float4* src = (const float4*)(W + base);
            float4 x = src[0], y = src[1];
            u16x8 o;
            o[0] = f2bf(x.x); o[1] = f2bf(x.y); o[2] = f2bf(x.z); o[3] = f2bf(x.w);
            o[4] = f2bf(y.x); o[5] = f2bf(y.y); o[6] = f2bf(y.z); o[7] = f2bf(y.w);
            *(u16x8*)(Wb + base) = o;
        }
        return;
    }
    __shared__ u16 tile[64][40];                      // pad: rows 80B (16B aligned)
    int b  = blk / TBLK_PER_B;
    int n0 = (blk % TBLK_PER_B) * TCHUNK;
    const float* inb = inp + (size_t)b * CIN_ * N_;
    #pragma unroll
    for (int it = 0; it < 8; ++it) {
        int idx = it * 256 + tid;
        int c = idx >> 6, n = idx & 63;
        if (n0 + n < N_) tile[n][c] = f2bf(inb[(size_t)c * N_ + n0 + n]);
    }
    __syncthreads();
    int n = tid >> 2, seg = tid & 3;
    if (n0 + n < N_) {
        u16x8 v = *(const u16x8*)&tile[n][seg * 8];
        *(u16x8*)(xt + ((size_t)b * XT_ROWS + n0 + n) * CIN_ + seg * 8) = v;
    }
}

// Gather + MFMA GEMM. A = W (o = lane&15), B = feats (node = lane&15).
// Each wave: 4 M-tiles of 16 nodes; block = 256 nodes.
__global__ __launch_bounds__(256) void conv_kernel(
    const u16* __restrict__ xt, const u16* __restrict__ Wb,
    const int* __restrict__ nbr, const float* __restrict__ bias,
    float* __restrict__ out)
{
    __shared__ u16 Wl[COUT_ * WPITCH];                // 53,760 B
    int tid = threadIdx.x;
    // stage W (bf16) into padded LDS rows: 3328 u16x8 chunks, 13 iters/thread
    for (int i = tid; i < 3328; i += 256) {
        int row = i / 104, col8 = i - row * 104;      // 104 * 8 = 832
        *(u16x8*)&Wl[row * WPITCH + col8 * 8] = *(const u16x8*)(Wb + i * 8);
    }
    __syncthreads();

    int blk   = blockIdx.x;
    int b     = blk / CBLK_PER_B;
    int node0 = (blk - b * CBLK_PER_B) * NPB;
    int lane  = tid & 63;
    int wv    = tid >> 6;
    int l15   = lane & 15, g = lane >> 4;

    const u16* xtb  = xt  + (size_t)b * XT_ROWS * CIN_;
    const int* nbb  = nbr + (size_t)b * N_ * K_;
    float*     outb = out + (size_t)b * COUT_ * N_;

    int nbase = node0 + wv * 64;
    const int* idxp[4];
    #pragma unroll
    for (int t = 0; t < 4; ++t) {
        int node = nbase + t * 16 + l15;
        if (node >= N_) node = N_ - 1;                // clamp: keep OOB reads in-bounds
        idxp[t] = nbb + (size_t)node * K_;
    }
    const u16* wl0 = &Wl[l15 * WPITCH + (g << 3)];

    f32x4 acc[4][2];
    #pragma unroll
    for (int t = 0; t < 4; ++t) { acc[t][0] = 0.0f; acc[t][1] = 0.0f; }

    #pragma unroll 2
    for (int kk = 0; kk < K_; ++kk) {
        bf16x8 a0 = *(const bf16x8*)(wl0 + kk * 32);                 // o = l15
        bf16x8 a1 = *(const bf16x8*)(wl0 + 16 * WPITCH + kk * 32);   // o = l15+16
        #pragma unroll
        for (int t = 0; t < 4; ++t) {
            int idx = idxp[t][kk];
            const u16* p = xtb + (((uint32_t)idx) << 5) + (g << 3);  // one 64B row / 4 lanes
            bf16x8 bf = *(const bf16x8*)p;
            acc[t][0] = __builtin_amdgcn_mfma_f32_16x16x32_bf16(a0, bf, acc[t][0], 0, 0, 0);
            acc[t][1] = __builtin_amdgcn_mfma_f32_16x16x32_bf16(a1, bf, acc[t][1], 0, 0, 0);
        }
    }

    float bs0[4], bs1[4];
    #pragma unroll
    for (int r = 0; r < 4; ++r) {
        bs0[r] = bias[g * 4 + r];
        bs1[r] = bias[g * 4 + r + 16];
    }
    #pragma unroll
    for (int t = 0; t < 4; ++t) {
        int node = nbase + t * 16 + l15;              // D col = lane&15 -> node
        if (node < N_) {
            #pragma unroll
            for (int r = 0; r < 4; ++r) {             // D row = g*4 + r -> o
                outb[(size_t)(g * 4 + r) * N_ + node]      = acc[t][0][r] + bs0[r];
                outb[(size_t)(g * 4 + r + 16) * N_ + node] = acc[t][1][r] + bs1[r];
            }
        }
    }
}

extern "C" void kernel_launch(void* const* d_in, const int* in_sizes, int n_in,
                              void* d_out, int out_size, void* d_ws, size_t ws_size,
                              hipStream_t stream) {
    (void)in_sizes; (void)n_in; (void)out_size; (void)ws_size;
    const float* inp  = (const float*)d_in[0];
    const int*   nbr  = (const int*)d_in[1];
    const float* W    = (const float*)d_in[2];
    const float* bias = (const float*)d_in[3];
    const float* fill = (const float*)d_in[4];
    float* out = (float*)d_out;

    u16* xt = (u16*)d_ws;                              // [B][N+1][32] bf16
    u16* Wb = (u16*)((char*)d_ws + XT_BYTES);          // [32][832] bf16

    prep_kernel<<<PREP_GRID, 256, 0, stream>>>(inp, W, fill, xt, Wb);
    conv_kernel<<<CONV_GRID, 256, 0, stream>>>(xt, Wb, nbr, bias, out);
}

// Round 3
// 95.075 us; speedup vs baseline: 1.5313x; 1.5313x over previous
//
#include <hip/hip_runtime.h>
#include <stdint.h>

typedef uint16_t u16;
typedef __attribute__((ext_vector_type(8))) short    bf16x8;  // 8 bf16 (4 VGPRs)
typedef __attribute__((ext_vector_type(8))) uint16_t u16x8;
typedef __attribute__((ext_vector_type(4))) float    f32x4;

#define B_    2
#define N_    100000
#define K_    26
#define CIN_  32
#define COUT_ 32

#define XT_ROWS  (N_ + 1)
#define XT_BYTES ((size_t)B_ * XT_ROWS * CIN_ * 2)   // 12,800,128 bytes

// ---- prep kernel geometry ----
#define TCHUNK      64
#define TBLK_PER_B  ((N_ + TCHUNK - 1) / TCHUNK)     // 1563
#define TBLKS       (B_ * TBLK_PER_B)                // 3126
#define WBLKS       13                               // 13 * 2048 = 26624 W elems
#define PREP_GRID   (TBLKS + 1 + WBLKS)

// ---- conv kernel geometry ----
#define NPB         128                              // nodes per block (4 waves x 32)
#define CBLK_PER_B  ((N_ + NPB - 1) / NPB)           // 782
#define CONV_GRID   (B_ * CBLK_PER_B)                // 1564

__device__ __forceinline__ u16 f2bf(float f) {
    union { float f; uint32_t u; } v; v.f = f;
    return (u16)((v.u + 0x7FFFu + ((v.u >> 16) & 1u)) >> 16);  // RNE
}

// Transpose inp [B][CIN][N] f32 -> xt [B][N+1][CIN] bf16 (64B rows),
// write fill row at n==N, convert W -> bf16.
__global__ __launch_bounds__(256) void prep_kernel(
    const float* __restrict__ inp, const float* __restrict__ W,
    const float* __restrict__ fill, u16* __restrict__ xt, u16* __restrict__ Wb)
{
    int tid = threadIdx.x;
    int blk = blockIdx.x;
    if (blk >= TBLKS) {
        int job = blk - TBLKS;
        if (job == 0) {
            if (tid < B_ * CIN_) {
                int b = tid >> 5, c = tid & 31;
                xt[((size_t)b * XT_ROWS + N_) * CIN_ + c] = f2bf(fill[c]);
            }
        } else {
            int base = (job - 1) * 2048 + tid * 8;   // exact: 13*2048 = 26624
            const float4* src = (const float4*)(W + base);
            float4 x = src[0], y = src[1];
            u16x8 o;
            o[0] = f2bf(x.x); o[1] = f2bf(x.y); o[2] = f2bf(x.z); o[3] = f2bf(x.w);
            o[4] = f2bf(y.x); o[5] = f2bf(y.y); o[6] = f2bf(y.z); o[7] = f2bf(y.w);
            *(u16x8*)(Wb + base) = o;
        }
        return;
    }
    __shared__ u16 tile[64][40];                      // pad: rows 80B (16B aligned)
    int b  = blk / TBLK_PER_B;
    int n0 = (blk % TBLK_PER_B) * TCHUNK;
    const float* inb = inp + (size_t)b * CIN_ * N_;
    #pragma unroll
    for (int it = 0; it < 8; ++it) {
        int idx = it * 256 + tid;
        int c = idx >> 6, n = idx & 63;
        if (n0 + n < N_) tile[n][c] = f2bf(inb[(size_t)c * N_ + n0 + n]);
    }
    __syncthreads();
    int n = tid >> 2, seg = tid & 3;
    if (n0 + n < N_) {
        u16x8 v = *(const u16x8*)&tile[n][seg * 8];
        *(u16x8*)(xt + ((size_t)b * XT_ROWS + n0 + n) * CIN_ + seg * 8) = v;
    }
}

// Gather + MFMA GEMM, no LDS (occupancy-first).
// A = W (o = lane&15), B = feats (node = lane&15).
// Each wave: 2 M-tiles of 16 nodes; block = 128 nodes.
__global__ __launch_bounds__(256, 6) void conv_kernel(
    const u16* __restrict__ xt, const u16* __restrict__ Wb,
    const int* __restrict__ nbr, const float* __restrict__ bias,
    float* __restrict__ out)
{
    int tid  = threadIdx.x;
    int blk  = blockIdx.x;
    int b    = blk / CBLK_PER_B;
    int node0 = (blk - b * CBLK_PER_B) * NPB;
    int lane = tid & 63;
    int wv   = tid >> 6;
    int l15  = lane & 15, g = lane >> 4;

    const u16* xtb  = xt  + (size_t)b * XT_ROWS * CIN_;
    const int* nbb  = nbr + (size_t)b * N_ * K_;
    float*     outb = out + (size_t)b * COUT_ * N_;

    int nbase = node0 + wv * 32;
    int n0c = nbase + l15;        if (n0c >= N_) n0c = N_ - 1;   // clamp tail
    int n1c = nbase + 16 + l15;   if (n1c >= N_) n1c = N_ - 1;
    const int* p0 = nbb + (size_t)n0c * K_;   // 104B rows -> int2 (8B) aligned
    const int* p1 = nbb + (size_t)n1c * K_;

    const u16* wg0 = Wb + l15 * (CIN_ * K_) + (g << 3);   // o = l15 row, g-th 8-chunk
    const u16* xg  = xtb + (g << 3);

    f32x4 acc[2][2];
    acc[0][0] = 0.0f; acc[0][1] = 0.0f; acc[1][0] = 0.0f; acc[1][1] = 0.0f;

    // software-pipelined index prefetch, distance = 2 int2-pairs
    int2 buf0[2], buf1[2];
    buf0[0] = *(const int2*)(p0);     buf1[0] = *(const int2*)(p1);
    buf0[1] = *(const int2*)(p0 + 2); buf1[1] = *(const int2*)(p1 + 2);

    #pragma unroll
    for (int kp = 0; kp < 13; ++kp) {                 // 13 pairs = K_=26
        int2 c0 = buf0[kp & 1], c1 = buf1[kp & 1];    // kp static under unroll
        if (kp < 11) {
            buf0[kp & 1] = *(const int2*)(p0 + 2 * kp + 4);
            buf1[kp & 1] = *(const int2*)(p1 + 2 * kp + 4);
        }
        // W fragments for kk = 2kp, 2kp+1 (predictable, L1/L2-resident)
        bf16x8 a0_0 = *(const bf16x8*)(wg0 + (2 * kp) * 32);
        bf16x8 a1_0 = *(const bf16x8*)(wg0 + 16 * (CIN_ * K_) + (2 * kp) * 32);
        bf16x8 a0_1 = *(const bf16x8*)(wg0 + (2 * kp + 1) * 32);
        bf16x8 a1_1 = *(const bf16x8*)(wg0 + 16 * (CIN_ * K_) + (2 * kp + 1) * 32);
        // gathers: one 64B xt row per 4 lanes
        bf16x8 f00 = *(const bf16x8*)(xg + (((uint32_t)c0.x) << 5));
        bf16x8 f10 = *(const bf16x8*)(xg + (((uint32_t)c1.x) << 5));
        bf16x8 f01 = *(const bf16x8*)(xg + (((uint32_t)c0.y) << 5));
        bf16x8 f11 = *(const bf16x8*)(xg + (((uint32_t)c1.y) << 5));
        acc[0][0] = __builtin_amdgcn_mfma_f32_16x16x32_bf16(a0_0, f00, acc[0][0], 0, 0, 0);
        acc[0][1] = __builtin_amdgcn_mfma_f32_16x16x32_bf16(a1_0, f00, acc[0][1], 0, 0, 0);
        acc[1][0] = __builtin_amdgcn_mfma_f32_16x16x32_bf16(a0_0, f10, acc[1][0], 0, 0, 0);
        acc[1][1] = __builtin_amdgcn_mfma_f32_16x16x32_bf16(a1_0, f10, acc[1][1], 0, 0, 0);
        acc[0][0] = __builtin_amdgcn_mfma_f32_16x16x32_bf16(a0_1, f01, acc[0][0], 0, 0, 0);
        acc[0][1] = __builtin_amdgcn_mfma_f32_16x16x32_bf16(a1_1, f01, acc[0][1], 0, 0, 0);
        acc[1][0] = __builtin_amdgcn_mfma_f32_16x16x32_bf16(a0_1, f11, acc[1][0], 0, 0, 0);
        acc[1][1] = __builtin_amdgcn_mfma_f32_16x16x32_bf16(a1_1, f11, acc[1][1], 0, 0, 0);
    }

    float bs0[4], bs1[4];
    #pragma unroll
    for (int r = 0; r < 4; ++r) {
        bs0[r] = bias[g * 4 + r];
        bs1[r] = bias[g * 4 + r + 16];
    }
    #pragma unroll
    for (int t = 0; t < 2; ++t) {
        int node = nbase + t * 16 + l15;              // D col = lane&15 -> node
        if (node < N_) {
            #pragma unroll
            for (int r = 0; r < 4; ++r) {             // D row = g*4 + r -> o
                outb[(size_t)(g * 4 + r) * N_ + node]      = acc[t][0][r] + bs0[r];
                outb[(size_t)(g * 4 + r + 16) * N_ + node] = acc[t][1][r] + bs1[r];
            }
        }
    }
}

extern "C" void kernel_launch(void* const* d_in, const int* in_sizes, int n_in,
                              void* d_out, int out_size, void* d_ws, size_t ws_size,
                              hipStream_t stream) {
    (void)in_sizes; (void)n_in; (void)out_size; (void)ws_size;
    const float* inp  = (const float*)d_in[0];
    const int*   nbr  = (const int*)d_in[1];
    const float* W    = (const float*)d_in[2];
    const float* bias = (const float*)d_in[3];
    const float* fill = (const float*)d_in[4];
    float* out = (float*)d_out;

    u16* xt = (u16*)d_ws;                              // [B][N+1][32] bf16
    u16* Wb = (u16*)((char*)d_ws + XT_BYTES);          // [32][832] bf16

    prep_kernel<<<PREP_GRID, 256, 0, stream>>>(inp, W, fill, xt, Wb);
    conv_kernel<<<CONV_GRID, 256, 0, stream>>>(xt, Wb, nbr, bias, out);
}

// Round 4
// 92.525 us; speedup vs baseline: 1.5734x; 1.0275x over previous
//
#include <hip/hip_runtime.h>
#include <stdint.h>

typedef uint16_t u16;
typedef __attribute__((ext_vector_type(8))) short    bf16x8;  // 8 bf16 (4 VGPRs)
typedef __attribute__((ext_vector_type(8))) uint16_t u16x8;
typedef __attribute__((ext_vector_type(4))) float    f32x4;

#define B_    2
#define N_    100000
#define K_    26
#define CIN_  32
#define COUT_ 32

#define XT_ROWS  (N_ + 1)
#define XT_BYTES ((size_t)B_ * XT_ROWS * CIN_ * 2)   // 12,800,128 bytes

// ---- prep kernel geometry ----
#define TCHUNK      64
#define TBLK_PER_B  ((N_ + TCHUNK - 1) / TCHUNK)     // 1563
#define TBLKS       (B_ * TBLK_PER_B)                // 3126
#define WBLKS       13                               // 13 * 2048 = 26624 W elems
#define PREP_GRID   (TBLKS + 1 + WBLKS)

// ---- conv kernel geometry ----
#define NPB         128                              // nodes per block (4 waves x 32)
#define CBLK_PER_B  ((N_ + NPB - 1) / NPB)           // 782
#define SLOTS       ((CBLK_PER_B + 3) / 4)           // 196 slots per XCD-half
#define CONV_GRID   (SLOTS * 8)                      // 1568 (few no-op blocks)

__device__ __forceinline__ u16 f2bf(float f) {
    union { float f; uint32_t u; } v; v.f = f;
    return (u16)((v.u + 0x7FFFu + ((v.u >> 16) & 1u)) >> 16);  // RNE
}

// Transpose inp [B][CIN][N] f32 -> xt [B][N+1][CIN] bf16 (64B rows),
// write fill row at n==N, convert W -> bf16.
__global__ __launch_bounds__(256) void prep_kernel(
    const float* __restrict__ inp, const float* __restrict__ W,
    const float* __restrict__ fill, u16* __restrict__ xt, u16* __restrict__ Wb)
{
    int tid = threadIdx.x;
    int blk = blockIdx.x;
    if (blk >= TBLKS) {
        int job = blk - TBLKS;
        if (job == 0) {
            if (tid < B_ * CIN_) {
                int b = tid >> 5, c = tid & 31;
                xt[((size_t)b * XT_ROWS + N_) * CIN_ + c] = f2bf(fill[c]);
            }
        } else {
            int base = (job - 1) * 2048 + tid * 8;   // exact: 13*2048 = 26624
            const float4* src = (const float4*)(W + base);
            float4 x = src[0], y = src[1];
            u16x8 o;
            o[0] = f2bf(x.x); o[1] = f2bf(x.y); o[2] = f2bf(x.z); o[3] = f2bf(x.w);
            o[4] = f2bf(y.x); o[5] = f2bf(y.y); o[6] = f2bf(y.z); o[7] = f2bf(y.w);
            *(u16x8*)(Wb + base) = o;
        }
        return;
    }
    __shared__ u16 tile[64][40];                      // pad: rows 80B (16B aligned)
    int b  = blk / TBLK_PER_B;
    int n0 = (blk % TBLK_PER_B) * TCHUNK;
    const float* inb = inp + (size_t)b * CIN_ * N_;
    #pragma unroll
    for (int it = 0; it < 8; ++it) {
        int idx = it * 256 + tid;
        int c = idx >> 6, n = idx & 63;
        if (n0 + n < N_) tile[n][c] = f2bf(inb[(size_t)c * N_ + n0 + n]);
    }
    __syncthreads();
    int n = tid >> 2, seg = tid & 3;
    if (n0 + n < N_) {
        u16x8 v = *(const u16x8*)&tile[n][seg * 8];
        *(u16x8*)(xt + ((size_t)b * XT_ROWS + n0 + n) * CIN_ + seg * 8) = v;
    }
}

#define MFMA16(a, b, c) __builtin_amdgcn_mfma_f32_16x16x32_bf16((a), (b), (c), 0, 0, 0)

// Gather + MFMA GEMM, no LDS, feat double-buffered pipeline.
// A = W (o = lane&15), B = feats (node = lane&15). Wave = 2 M-tiles x 16 nodes.
// Block swizzle: batch 0 -> XCDs 0-3, batch 1 -> XCDs 4-7 (bid%8 -> XCD heuristic).
__global__ __launch_bounds__(256, 5) void conv_kernel(
    const u16* __restrict__ xt, const u16* __restrict__ Wb,
    const int* __restrict__ nbr, const float* __restrict__ bias,
    float* __restrict__ out)
{
    int tid  = threadIdx.x;
    int bid  = blockIdx.x;
    int xcd  = bid & 7, slot = bid >> 3;
    int b    = xcd >> 2;
    int local = slot * 4 + (xcd & 3);
    if (local >= CBLK_PER_B) return;
    int node0 = local * NPB;
    int lane = tid & 63;
    int wv   = tid >> 6;
    int l15  = lane & 15, g = lane >> 4;

    const u16* xtb  = xt  + (size_t)b * XT_ROWS * CIN_;
    const int* nbb  = nbr + (size_t)b * N_ * K_;
    float*     outb = out + (size_t)b * COUT_ * N_;

    int nbase = node0 + wv * 32;
    int n0c = nbase + l15;        if (n0c >= N_) n0c = N_ - 1;   // clamp tail
    int n1c = nbase + 16 + l15;   if (n1c >= N_) n1c = N_ - 1;
    const int* p0 = nbb + (size_t)n0c * K_;   // 104B rows -> int2 (8B) aligned
    const int* p1 = nbb + (size_t)n1c * K_;

    const u16* wg0 = Wb + l15 * (CIN_ * K_) + (g << 3);   // o = l15 row, g-th 8-chunk
    const u16* xg  = xtb + (g << 3);

    f32x4 acc[2][2];
    acc[0][0] = 0.0f; acc[0][1] = 0.0f; acc[1][0] = 0.0f; acc[1][1] = 0.0f;

    // idx ring (depth 2) + feat double buffer
    int2 qr0[2], qr1[2];
    bf16x8 fb[2][4];
    qr0[0] = *(const int2*)(p0);     qr1[0] = *(const int2*)(p1);
    qr0[1] = *(const int2*)(p0 + 2); qr1[1] = *(const int2*)(p1 + 2);
    fb[0][0] = *(const bf16x8*)(xg + (((uint32_t)qr0[0].x) << 5));
    fb[0][1] = *(const bf16x8*)(xg + (((uint32_t)qr1[0].x) << 5));
    fb[0][2] = *(const bf16x8*)(xg + (((uint32_t)qr0[0].y) << 5));
    fb[0][3] = *(const bf16x8*)(xg + (((uint32_t)qr1[0].y) << 5));

    #pragma unroll
    for (int kp = 0; kp < 13; ++kp) {                 // 13 pairs = K_=26
        const int cur = kp & 1, nxt = cur ^ 1;
        // W fragments for this iter — issued BEFORE next gathers so the MFMA
        // wait on W does not drain the prefetched gathers (vmcnt is in-order).
        bf16x8 a0_0 = *(const bf16x8*)(wg0 + (2 * kp) * 32);
        bf16x8 a1_0 = *(const bf16x8*)(wg0 + 16 * (CIN_ * K_) + (2 * kp) * 32);
        bf16x8 a0_1 = *(const bf16x8*)(wg0 + (2 * kp + 1) * 32);
        bf16x8 a1_1 = *(const bf16x8*)(wg0 + 16 * (CIN_ * K_) + (2 * kp + 1) * 32);
        if (kp < 12) {
            int2 c0 = qr0[nxt], c1 = qr1[nxt];        // pair kp+1
            fb[nxt][0] = *(const bf16x8*)(xg + (((uint32_t)c0.x) << 5));
            fb[nxt][1] = *(const bf16x8*)(xg + (((uint32_t)c1.x) << 5));
            fb[nxt][2] = *(const bf16x8*)(xg + (((uint32_t)c0.y) << 5));
            fb[nxt][3] = *(const bf16x8*)(xg + (((uint32_t)c1.y) << 5));
            if (kp < 11) {
                qr0[cur] = *(const int2*)(p0 + 2 * kp + 4);   // pair kp+2
                qr1[cur] = *(const int2*)(p1 + 2 * kp + 4);
            }
        }
        acc[0][0] = MFMA16(a0_0, fb[cur][0], acc[0][0]);
        acc[0][1] = MFMA16(a1_0, fb[cur][0], acc[0][1]);
        acc[1][0] = MFMA16(a0_0, fb[cur][1], acc[1][0]);
        acc[1][1] = MFMA16(a1_0, fb[cur][1], acc[1][1]);
        acc[0][0] = MFMA16(a0_1, fb[cur][2], acc[0][0]);
        acc[0][1] = MFMA16(a1_1, fb[cur][2], acc[0][1]);
        acc[1][0] = MFMA16(a0_1, fb[cur][3], acc[1][0]);
        acc[1][1] = MFMA16(a1_1, fb[cur][3], acc[1][1]);
    }

    float bs0[4], bs1[4];
    #pragma unroll
    for (int r = 0; r < 4; ++r) {
        bs0[r] = bias[g * 4 + r];
        bs1[r] = bias[g * 4 + r + 16];
    }
    #pragma unroll
    for (int t = 0; t < 2; ++t) {
        int node = nbase + t * 16 + l15;              // D col = lane&15 -> node
        if (node < N_) {
            #pragma unroll
            for (int r = 0; r < 4; ++r) {             // D row = g*4 + r -> o
                outb[(size_t)(g * 4 + r) * N_ + node]      = acc[t][0][r] + bs0[r];
                outb[(size_t)(g * 4 + r + 16) * N_ + node] = acc[t][1][r] + bs1[r];
            }
        }
    }
}

extern "C" void kernel_launch(void* const* d_in, const int* in_sizes, int n_in,
                              void* d_out, int out_size, void* d_ws, size_t ws_size,
                              hipStream_t stream) {
    (void)in_sizes; (void)n_in; (void)out_size; (void)ws_size;
    const float* inp  = (const float*)d_in[0];
    const int*   nbr  = (const int*)d_in[1];
    const float* W    = (const float*)d_in[2];
    const float* bias = (const float*)d_in[3];
    const float* fill = (const float*)d_in[4];
    float* out = (float*)d_out;

    u16* xt = (u16*)d_ws;                              // [B][N+1][32] bf16
    u16* Wb = (u16*)((char*)d_ws + XT_BYTES);          // [32][832] bf16

    prep_kernel<<<PREP_GRID, 256, 0, stream>>>(inp, W, fill, xt, Wb);
    conv_kernel<<<CONV_GRID, 256, 0, stream>>>(xt, Wb, nbr, bias, out);
}